// Round 12
// baseline (1976.037 us; speedup 1.0000x reference)
//
#include <hip/hip_runtime.h>
#include <hip/hip_bf16.h>
#include <math.h>

// MDN-RNN: B=128, T=512, Z=32, A=3, H=256, K=5, IN=35, 4H=1024, MDN=325
#define T_LEN 512
#define B_SZ  128
#define H_DIM 256
#define G_DIM 1024
#define IN_D  35
#define MDN_D 325
#define K_MIX 5

#define NSLICE 4     // gate-dim slices per group (64 h-cols x 4 gates each)
#define NGRP   64    // groups of 2 batches -> 256 blocks = 1/CU

// d_out layout: log_pi[B,T,5] | mu[B,T,5,32] | sigma[B,T,5,32] | c[B,256] | h[B,256]
static constexpr long OFF_MU    = 327680L;
static constexpr long OFF_SIGMA = 10813440L;
static constexpr long OFF_C     = 21299200L;
static constexpr long OFF_H     = 21331968L;

// ws layout (~34 MB; ws >= 64 MiB proven in round 1)
static constexpr size_t WS_OUT = 0;          // bf16 outs: B*T*H*2 = 33,554,432 B
static constexpr size_t WS_HG  = 33554432;   // 64 grp * 2 par * 256 k * 2 b f32 = 512 KB

typedef unsigned uint2v  __attribute__((ext_vector_type(2)));
typedef float    float2v __attribute__((ext_vector_type(2)));
typedef float    float4v __attribute__((ext_vector_type(4)));

__device__ __forceinline__ float fast_sigmoid(float x) { return 1.0f / (1.0f + __expf(-x)); }
__device__ __forceinline__ float fast_tanh(float x) {
    return 1.0f - 2.0f / (__expf(2.0f * x) + 1.0f);
}

// acc.lo += w.lo*h.lo ; acc.hi += w.hi*h.lo   (broadcast LOW half of h-pair)
__device__ __forceinline__ void pk_fma_lo(float2v& acc, float2v w, float2v h) {
    asm("v_pk_fma_f32 %0, %1, %2, %0 op_sel:[0,0,0] op_sel_hi:[1,0,1]"
        : "+v"(acc) : "v"(w), "v"(h));
}
// acc.lo += w.lo*h.hi ; acc.hi += w.hi*h.hi   (broadcast HIGH half of h-pair)
__device__ __forceinline__ void pk_fma_hi(float2v& acc, float2v w, float2v h) {
    asm("v_pk_fma_f32 %0, %1, %2, %0 op_sel:[0,1,0] op_sel_hi:[1,1,1]"
        : "+v"(acc) : "v"(w), "v"(h));
}

// Single-barrier step: octet (8 lanes) = h-col j; lane (kq,u) computes gates
// {u,u+2} of col j for BOTH batches over k-chunk kq. kq-butterfly + xor4 swap
// -> every lane holds all 4 gate sums -> nonlin in-register (no g_red, no 2nd
// barrier). Barrier is RAW (lgkmcnt only): publish/outs store acks are never
// drained. Poll = r6-proven serial vmcnt(0) tagged spin (in-order vmcnt makes
// same-wave publish stores harmless). hbuf/hg layout [par][k][b] so publish =
// one dwordx2, poll = one dwordx2, FMA reads (k:b0,b1,k+1:b0,b1) float4s.
// Roles within each octet: lane0 publish; lanes1-3 poll; lanes4-5 stage x.
__global__ __launch_bounds__(512, 1) void lstm12_kernel(
    const float* __restrict__ z_t, const float* __restrict__ a_t,
    const float* __restrict__ Wx,  const float* __restrict__ Wh,
    const float* __restrict__ bias,
    float* __restrict__ h_glb,
    __hip_bfloat16* __restrict__ outs,
    float* __restrict__ out_c, float* __restrict__ out_h)
{
    const int bid = blockIdx.x;
    const int gr  = bid & 63;
    const int s   = bid >> 6;
    const int tid = threadIdx.x;
    const int kq  = tid & 3;               // k-chunk [kq*64, kq*64+64)
    const int u   = (tid >> 2) & 1;        // gate set {u, u+2}
    const int j   = tid >> 3;              // h-col within slice, 0..63
    const int oct = tid & 7;               // role selector
    const int cu0 = u * 256 + s * 64 + j;
    const int cu1 = (u + 2) * 256 + s * 64 + j;

    __shared__ __align__(16) float hbuf[2][256][2];   // [par][k][b] (tagged f32)
    __shared__ __align__(16) float x_lds[2][2][44];   // [par][b][35 + zero pad]

    for (int i = tid; i < 512; i += 512) ((float*)hbuf[1])[i] = 0.0f;   // h(-1)=0
    if (tid < 36) {   // zero x pads [35..43], both parities/batches
        int p = tid / 18, b = (tid / 9) & 1, kp = 35 + tid % 9;
        x_lds[p][b][kp] = 0.0f;
    }

    // ---- persistent weights in VGPRs (loaded once, pinned vs remat) ----
    float2v W2[64];
    #pragma unroll
    for (int i = 0; i < 64; ++i) {
        const size_t r = (size_t)(kq * 64 + i) * G_DIM;
        W2[i].x = Wh[r + cu0];
        W2[i].y = Wh[r + cu1];
    }
    float2v X2[10];
    #pragma unroll
    for (int i = 0; i < 10; ++i) {
        int xk = kq * 10 + i;
        bool ok = (xk < IN_D);
        X2[i].x = ok ? Wx[(size_t)xk * G_DIM + cu0] : 0.0f;
        X2[i].y = ok ? Wx[(size_t)xk * G_DIM + cu1] : 0.0f;
    }
    #pragma unroll
    for (int i = 0; i < 64; ++i) asm volatile("" : "+v"(W2[i]));
    #pragma unroll
    for (int i = 0; i < 10; ++i) asm volatile("" : "+v"(X2[i]));

    // all lanes carry bias + replicated cell state for col j (both batches)
    const float bci = bias[0 * 256 + s * 64 + j];
    const float bcf = bias[1 * 256 + s * 64 + j];
    const float bcg = bias[2 * 256 + s * 64 + j];
    const float bco = bias[3 * 256 + s * 64 + j];
    float c0 = 0.0f, c1 = 0.0f;

    // poller mapping (oct 1..3): one foreign dwordx2 (both batches of one k)
    const bool is_p = (oct >= 1 && oct <= 3);
    const int  pidx = j * 3 + (oct - 1);                 // 0..191
    const int  kk   = pidx + ((pidx >= s * 64) ? 64 : 0);

    // stager mapping (oct 4..5): one (batch,k) each, 2-deep x reg pipeline
    const int  sq    = j * 2 + (oct - 4);
    const bool is_st = (oct == 4 || oct == 5) && (sq < 2 * IN_D);
    const int  sb    = (sq >= IN_D) ? 1 : 0;
    const int  sk    = sq - IN_D * sb;
    float xv_next = 0.0f;

    const int batch0 = gr * 2;
    float* hg = h_glb + (size_t)gr * 1024;   // [par][k][b]

    if (is_st) {
        const size_t r0 = (size_t)(batch0 + sb) * T_LEN;
        x_lds[0][sb][sk] = (sk < 32) ? z_t[(r0 + 0) * 32 + sk]
                                     : a_t[(r0 + 0) * 3 + (sk - 32)];
        xv_next = (sk < 32) ? z_t[(r0 + 1) * 32 + sk]
                            : a_t[(r0 + 1) * 3 + (sk - 32)];
    }
    __syncthreads();   // once, pre-loop (full drain OK here)

    for (int t = 0; t < T_LEN; ++t) {
        // ---- (A) poll foreign tagged h(t-1): serial vmcnt(0) spin ----
        if (t > 0 && is_p) {
            const unsigned want = (unsigned)((t - 1) & 3);
            const float* ap = hg + ((t - 1) & 1) * 512 + kk * 2;
            uint2v uu;
            do {
                asm volatile("global_load_dwordx2 %0, %1, off sc0 sc1\n\t"
                             "s_waitcnt vmcnt(0)"
                             : "=v"(uu) : "v"(ap) : "memory");
            } while ((uu.x & 3u) != want || (uu.y & 3u) != want);
            float2v hv; hv.x = __uint_as_float(uu.x); hv.y = __uint_as_float(uu.y);
            *(float2v*)&hbuf[(t - 1) & 1][kk][0] = hv;
        }
        // the ONE barrier: raw, LDS-ordered only — store acks float across it
        asm volatile("s_waitcnt lgkmcnt(0)\n\ts_barrier" ::: "memory");

        // ---- (B) FMA: gates {u,u+2} x 2 batches x 64 k per lane ----
        float2v acc0 = {0.0f, 0.0f}, acc1 = {0.0f, 0.0f};
        {
            const float4v* hp = (const float4v*)&hbuf[(t + 1) & 1][kq * 64][0];
            #pragma unroll
            for (int i2 = 0; i2 < 32; ++i2) {
                float4v hv = hp[i2];                     // (k:b0,b1, k+1:b0,b1)
                float2v lo = __builtin_shufflevector(hv, hv, 0, 1);
                float2v hi = __builtin_shufflevector(hv, hv, 2, 3);
                pk_fma_lo(acc0, W2[2*i2],     lo);   // b0 * W[k]
                pk_fma_hi(acc1, W2[2*i2],     lo);   // b1 * W[k]
                pk_fma_lo(acc0, W2[2*i2 + 1], hi);   // b0 * W[k+1]
                pk_fma_hi(acc1, W2[2*i2 + 1], hi);   // b1 * W[k+1]
            }
            const float* xb0 = &x_lds[t & 1][0][kq * 10];
            const float* xb1 = &x_lds[t & 1][1][kq * 10];
            #pragma unroll
            for (int i = 0; i < 5; ++i) {
                float2v xv0 = *(const float2v*)&xb0[2 * i];
                float2v xv1 = *(const float2v*)&xb1[2 * i];
                pk_fma_lo(acc0, X2[2*i],   xv0); pk_fma_hi(acc0, X2[2*i+1], xv0);
                pk_fma_lo(acc1, X2[2*i],   xv1); pk_fma_hi(acc1, X2[2*i+1], xv1);
            }
        }
        float a00 = acc0.x, a01 = acc0.y;   // b0: gate u, gate u+2
        float a10 = acc1.x, a11 = acc1.y;   // b1
        // kq butterfly (masks 1,2) -> full k-sums
        a00 += __shfl_xor(a00, 1, 64); a00 += __shfl_xor(a00, 2, 64);
        a01 += __shfl_xor(a01, 1, 64); a01 += __shfl_xor(a01, 2, 64);
        a10 += __shfl_xor(a10, 1, 64); a10 += __shfl_xor(a10, 2, 64);
        a11 += __shfl_xor(a11, 1, 64); a11 += __shfl_xor(a11, 2, 64);
        // u-swap (mask 4): receive partner's two gates
        float r00 = __shfl_xor(a00, 4, 64);
        float r01 = __shfl_xor(a01, 4, 64);
        float r10 = __shfl_xor(a10, 4, 64);
        float r11 = __shfl_xor(a11, 4, 64);
        float gi0 = (u ? r00 : a00) + bci, gf0 = (u ? a00 : r00) + bcf;
        float gg0 = (u ? r01 : a01) + bcg, go0 = (u ? a01 : r01) + bco;
        float gi1 = (u ? r10 : a10) + bci, gf1 = (u ? a10 : r10) + bcf;
        float gg1 = (u ? r11 : a11) + bcg, go1 = (u ? a11 : r11) + bco;

        // ---- (C) nonlin (redundant per octet -> no cross-lane handoff) ----
        float iv0 = fast_sigmoid(gi0), fv0 = fast_sigmoid(gf0), ov0 = fast_sigmoid(go0);
        c0 = fmaf(fv0, c0, iv0 * fast_tanh(gg0));
        float h0 = ov0 * fast_tanh(c0);
        float iv1 = fast_sigmoid(gi1), fv1 = fast_sigmoid(gf1), ov1 = fast_sigmoid(go1);
        c1 = fmaf(fv1, c1, iv1 * fast_tanh(gg1));
        float h1 = ov1 * fast_tanh(c1);

        if (oct == 0) {   // publisher: one tagged dwordx2 (both batches)
            const unsigned tg = (unsigned)(t & 3);
            float2v hw;
            hw.x = __uint_as_float((__float_as_uint(h0) & ~3u) | tg);
            hw.y = __uint_as_float((__float_as_uint(h1) & ~3u) | tg);
            float* dst = hg + (t & 1) * 512 + (s * 64 + j) * 2;
            asm volatile("global_store_dwordx2 %0, %1, off sc0 sc1"
                         :: "v"(dst), "v"(hw) : "memory");
            *(float2v*)&hbuf[t & 1][s * 64 + j][0] = hw;   // own k: no IC trip
            outs[((size_t)batch0 * T_LEN + t) * H_DIM + s * 64 + j] = __float2bfloat16(h0);
            outs[((size_t)(batch0 + 1) * T_LEN + t) * H_DIM + s * 64 + j] = __float2bfloat16(h1);
            if (t == T_LEN - 1) {
                out_c[batch0 * H_DIM + s * 64 + j] = c0;
                out_c[(batch0 + 1) * H_DIM + s * 64 + j] = c1;
                out_h[batch0 * H_DIM + s * 64 + j] = h0;
                out_h[(batch0 + 1) * H_DIM + s * 64 + j] = h1;
            }
        }
        if (is_st && t + 1 < T_LEN) {   // stage x(t+1), prefetch x(t+2)
            x_lds[(t + 1) & 1][sb][sk] = xv_next;
            if (t + 2 < T_LEN) {
                const size_t r0 = (size_t)(batch0 + sb) * T_LEN;
                xv_next = (sk < 32) ? z_t[(r0 + t + 2) * 32 + sk]
                                    : a_t[(r0 + t + 2) * 3 + (sk - 32)];
            }
        }
        // loop: next barrier (lgkmcnt+s_barrier) orders hbuf/x_lds for FMA
    }
}

// mdn = outputs(bf16) @ Wd + bd, fused log_softmax(log_pi) and exp(log_sigma)+1e-6.
// (r6-proven 16-row version, ~107 us)
__global__ __launch_bounds__(256, 1) void mdn_kernel(
    const unsigned short* __restrict__ outputs, const float* __restrict__ Wd,
    const float* __restrict__ bd, float* __restrict__ out)
{
    __shared__ __align__(16) float hT[H_DIM * 16];   // hT[k*16 + r]
    __shared__ float lp[16][K_MIX];

    const int tid = threadIdx.x;
    const long row0 = (long)blockIdx.x * 16;

    for (int idx = tid; idx < H_DIM * 16; idx += 256) {
        int r = idx >> 8;
        int k = idx & (H_DIM - 1);
        unsigned int u = outputs[(row0 + r) * H_DIM + k];
        hT[k * 16 + r] = __uint_as_float(u << 16);
    }
    __syncthreads();

    const int  cA = tid;
    const int  cB = tid + 256;
    const bool vB = (cB < MDN_D);
    const float bA = bd[cA];
    const float bB = vB ? bd[cB] : 0.0f;
    float accA[16], accB[16];
    #pragma unroll
    for (int r = 0; r < 16; ++r) { accA[r] = bA; accB[r] = bB; }

    for (int k = 0; k < H_DIM; ++k) {
        float wA = Wd[(size_t)k * MDN_D + cA];
        float wB = vB ? Wd[(size_t)k * MDN_D + cB] : 0.0f;
        const float4* hp = (const float4*)(hT + k * 16);
        float4 h0 = hp[0], h1 = hp[1], h2 = hp[2], h3 = hp[3];
        float hr[16] = { h0.x,h0.y,h0.z,h0.w, h1.x,h1.y,h1.z,h1.w,
                         h2.x,h2.y,h2.z,h2.w, h3.x,h3.y,h3.z,h3.w };
        #pragma unroll
        for (int r = 0; r < 16; ++r) {
            accA[r] = fmaf(hr[r], wA, accA[r]);
            accB[r] = fmaf(hr[r], wB, accB[r]);
        }
    }

    float* out_mu = out + OFF_MU;
    float* out_sg = out + OFF_SIGMA;
    #pragma unroll
    for (int r = 0; r < 16; ++r) {
        long row = row0 + r;
        float v = accA[r];
        if (cA < K_MIX)            lp[r][cA] = v;
        else if (cA < K_MIX + 160) out_mu[row * 160 + (cA - K_MIX)] = v;
        else                       out_sg[row * 160 + (cA - 165)]   = __expf(v) + 1e-6f;
        if (vB)                    out_sg[row * 160 + (cB - 165)]   = __expf(accB[r]) + 1e-6f;
    }
    __syncthreads();

    if (tid < 16) {
        int r = tid;
        long row = row0 + r;
        float v0 = lp[r][0], v1 = lp[r][1], v2 = lp[r][2], v3 = lp[r][3], v4 = lp[r][4];
        float m = fmaxf(fmaxf(fmaxf(v0, v1), fmaxf(v2, v3)), v4);
        float sum = __expf(v0-m) + __expf(v1-m) + __expf(v2-m) + __expf(v3-m) + __expf(v4-m);
        float ls = m + __logf(sum);
        out[row*5 + 0] = v0 - ls;
        out[row*5 + 1] = v1 - ls;
        out[row*5 + 2] = v2 - ls;
        out[row*5 + 3] = v3 - ls;
        out[row*5 + 4] = v4 - ls;
    }
}

extern "C" void kernel_launch(void* const* d_in, const int* in_sizes, int n_in,
                              void* d_out, int out_size, void* d_ws, size_t ws_size,
                              hipStream_t stream)
{
    const float* z_t = (const float*)d_in[0];
    const float* a_t = (const float*)d_in[1];
    const float* Wx  = (const float*)d_in[2];
    const float* Wh  = (const float*)d_in[3];
    const float* b   = (const float*)d_in[4];
    const float* Wd  = (const float*)d_in[5];
    const float* bd  = (const float*)d_in[6];
    float* out = (float*)d_out;

    char* ws = (char*)d_ws;
    __hip_bfloat16* outs = (__hip_bfloat16*)(ws + WS_OUT);
    float* h_glb         = (float*)(ws + WS_HG);

    lstm12_kernel<<<NGRP * NSLICE, 512, 0, stream>>>(z_t, a_t, Wx, Wh, b,
                                                     h_glb, outs,
                                                     out + OFF_C, out + OFF_H);
    mdn_kernel<<<(B_SZ * T_LEN) / 16, 256, 0, stream>>>((const unsigned short*)outs,
                                                        Wd, bd, out);
}

// Round 13
// 1274.393 us; speedup vs baseline: 1.5506x; 1.5506x over previous
//
#include <hip/hip_runtime.h>
#include <hip/hip_bf16.h>
#include <math.h>

// MDN-RNN: B=128, T=512, Z=32, A=3, H=256, K=5, IN=35, 4H=1024, MDN=325
#define T_LEN 512
#define B_SZ  128
#define H_DIM 256
#define G_DIM 1024
#define IN_D  35
#define MDN_D 325
#define K_MIX 5

#define NSLICE 4     // gate-dim slices per group (each owns 64 h-cols x 4 gates)
#define BG     2     // batches per group
#define NGRP   64    // 128 / BG   -> 256 blocks total = 1/CU

// d_out layout: log_pi[B,T,5] | mu[B,T,5,32] | sigma[B,T,5,32] | c[B,256] | h[B,256]
static constexpr long OFF_MU    = 327680L;
static constexpr long OFF_SIGMA = 10813440L;
static constexpr long OFF_C     = 21299200L;
static constexpr long OFF_H     = 21331968L;

// ws layout (~34 MB; ws >= 64 MiB proven in round 1)
static constexpr size_t WS_OUT = 0;          // bf16 outs: B*T*H*2 = 33,554,432 B
static constexpr size_t WS_HG  = 33554432;   // 64 grp * 2 par * 2 b * 256 f32 = 512 KB

typedef unsigned uint2v  __attribute__((ext_vector_type(2)));
typedef float    float2v __attribute__((ext_vector_type(2)));
typedef float    float4v __attribute__((ext_vector_type(4)));

__device__ __forceinline__ float fast_sigmoid(float x) { return 1.0f / (1.0f + __expf(-x)); }
__device__ __forceinline__ float fast_tanh(float x) {
    return 1.0f - 2.0f / (__expf(2.0f * x) + 1.0f);
}

// result.lo = s0.lo*s1.lo + acc.lo ; result.hi = s0.hi*s1.LO + acc.hi  (broadcast s1.lo)
__device__ __forceinline__ void pk_fma_lo(float2v& acc, float2v s0, float2v s1) {
    asm("v_pk_fma_f32 %0, %1, %2, %0 op_sel:[0,0,0] op_sel_hi:[1,0,1]"
        : "+v"(acc) : "v"(s0), "v"(s1));
}
// result.lo = s0.lo*s1.HI + acc.lo ; result.hi = s0.hi*s1.hi + acc.hi  (broadcast s1.hi)
__device__ __forceinline__ void pk_fma_hi(float2v& acc, float2v s0, float2v s1) {
    asm("v_pk_fma_f32 %0, %1, %2, %0 op_sel:[0,1,0] op_sel_hi:[1,1,1]"
        : "+v"(acc) : "v"(s0), "v"(s1));
}

// ===================== LSTM: round-6 kernel, verbatim (proven 1085 us) ==========
// 256 blocks (group=bid&63, slice=bid>>6), 512 threads.
// Weights VGPR-resident, PINNED via opaque asm (defeats per-step rematerialization).
// Inner loop = v_pk_fma_f32, columns paired, h broadcast via op_sel.
// h exchange: self-validating dwords (h in (-1,1); low 2 mantissa bits = t&3);
// waves 0-1 write+publish, waves 2-4 poll foreign dwords, wave 6 stages x(t+1).
__global__ __launch_bounds__(512, 1) void lstm6_kernel(
    const float* __restrict__ z_t, const float* __restrict__ a_t,
    const float* __restrict__ Wx,  const float* __restrict__ Wh,
    const float* __restrict__ bias,
    float* __restrict__ h_glb,
    __hip_bfloat16* __restrict__ outs,
    float* __restrict__ out_c, float* __restrict__ out_h)
{
    const int bid = blockIdx.x;
    const int gr  = bid & 63;
    const int s   = bid >> 6;
    const int tid = threadIdx.x;
    const int cg  = tid >> 2;              // cols {2cg, 2cg+1} of this 256-col slice
    const int kq  = tid & 3;               // k-range [kq*64, kq*64+64)
    const int lc0 = cg * 2;
    const int gate = lc0 >> 6;
    const int j0   = lc0 & 63;
    const int gcol0 = gate * 256 + s * 64 + j0;

    __shared__ __align__(16) float h_lds[BG][4][68];   // kq sections padded (+4)
    __shared__ __align__(16) float x_lds[BG][44];      // 40 used (4x10 k-split), pad 0
    __shared__ __align__(16) float g_red[BG][256];

    for (int i = tid; i < BG * 4 * 68; i += 512) ((float*)h_lds)[i] = 0.0f;  // h(-1)=0
    if (tid < BG * 9) { int b = tid / 9, k = tid - 9 * b; x_lds[b][35 + k] = 0.0f; }

    // ---- persistent weights in VGPRs: load once, then PIN (no remat possible) ----
    float2v W2[64];
    #pragma unroll
    for (int i = 0; i < 64; ++i) {
        const size_t r = (size_t)(kq * 64 + i) * G_DIM;
        W2[i].x = Wh[r + gcol0];
        W2[i].y = Wh[r + gcol0 + 1];
    }
    float2v X2[10];
    #pragma unroll
    for (int i = 0; i < 10; ++i) {
        int xk = kq * 10 + i;
        bool ok = (xk < IN_D);
        X2[i].x = ok ? Wx[(size_t)xk * G_DIM + gcol0]     : 0.0f;
        X2[i].y = ok ? Wx[(size_t)xk * G_DIM + gcol0 + 1] : 0.0f;
    }
    #pragma unroll
    for (int i = 0; i < 64; ++i) asm volatile("" : "+v"(W2[i]));
    #pragma unroll
    for (int i = 0; i < 10; ++i) asm volatile("" : "+v"(X2[i]));

    // writer role (tid<128): batch cb, h-col cj of this slice
    const int cb = tid >> 6;
    const int cj = tid & 63;
    const float bc0 = bias[0 * 256 + s * 64 + cj];
    const float bc1 = bias[1 * 256 + s * 64 + cj];
    const float bc2 = bias[2 * 256 + s * 64 + cj];
    const float bc3 = bias[3 * 256 + s * 64 + cj];
    float c_reg = 0.0f;

    // poller role (tid in [128,320)): q -> foreign dword pair (b, kk)
    const int q  = tid - 128;              // 0..191
    const int pb = (q >= 96) ? 1 : 0;
    const int pp = q - 96 * pb;            // 0..95
    const int pk0 = pp * 2;
    const int pkk = pk0 + ((pk0 >= s * 64) ? 64 : 0);   // skip own slice's 64-chunk

    const int batch0 = gr * BG;
    float* hg = h_glb + (size_t)gr * (2 * BG * H_DIM);   // [2][BG][256]

    // ---- pre-loop: stage x(0) ----
    if (tid >= 384 && tid < 448) {
        int qq = tid - 384, b = qq >> 5, k = qq & 31;
        x_lds[b][k] = z_t[((size_t)(batch0 + b) * T_LEN + 0) * 32 + k];
    } else if (tid >= 448 && tid < 448 + BG * 3) {
        int qq = tid - 448, b = (qq >= 3), k = qq - 3 * b;
        x_lds[b][32 + k] = a_t[((size_t)(batch0 + b) * T_LEN + 0) * 3 + k];
    }
    __syncthreads();

    for (int t = 0; t < T_LEN; ++t) {
        // ---- (A) pollers fetch foreign h(t-1): self-validating dword pairs ----
        if (t > 0 && tid >= 128 && tid < 320) {
            const unsigned want = (unsigned)((t - 1) & 3);
            const float* ap = hg + ((t - 1) & 1) * (BG * H_DIM) + pb * H_DIM + pkk;
            uint2v u;
            do {
                asm volatile("global_load_dwordx2 %0, %1, off sc0 sc1\n\t"
                             "s_waitcnt vmcnt(0)"
                             : "=v"(u) : "v"(ap) : "memory");
            } while ((u.x & 3u) != want || (u.y & 3u) != want);
            float* dst = &h_lds[pb][pkk >> 6][pkk & 63];
            dst[0] = __uint_as_float(u.x);
            dst[1] = __uint_as_float(u.y);
        }
        __syncthreads();   // B1: h_lds + x_lds(t) ready

        // ---- (B) packed FMA: 2 batches x col-pair x 64 k per thread ----
        float2v acc0 = {0.0f, 0.0f}, acc1 = {0.0f, 0.0f};
        {
            const float4v* hp0 = (const float4v*)h_lds[0][kq];
            const float4v* hp1 = (const float4v*)h_lds[1][kq];
            #pragma unroll
            for (int i4 = 0; i4 < 16; ++i4) {
                float4v hv0 = hp0[i4];
                float4v hv1 = hp1[i4];
                float2v h0lo = __builtin_shufflevector(hv0, hv0, 0, 1);
                float2v h0hi = __builtin_shufflevector(hv0, hv0, 2, 3);
                float2v h1lo = __builtin_shufflevector(hv1, hv1, 0, 1);
                float2v h1hi = __builtin_shufflevector(hv1, hv1, 2, 3);
                pk_fma_lo(acc0, W2[4*i4+0], h0lo); pk_fma_lo(acc1, W2[4*i4+0], h1lo);
                pk_fma_hi(acc0, W2[4*i4+1], h0lo); pk_fma_hi(acc1, W2[4*i4+1], h1lo);
                pk_fma_lo(acc0, W2[4*i4+2], h0hi); pk_fma_lo(acc1, W2[4*i4+2], h1hi);
                pk_fma_hi(acc0, W2[4*i4+3], h0hi); pk_fma_hi(acc1, W2[4*i4+3], h1hi);
            }
            #pragma unroll
            for (int i = 0; i < 5; ++i) {
                float2v xv0 = *(const float2v*)&x_lds[0][kq * 10 + 2 * i];
                float2v xv1 = *(const float2v*)&x_lds[1][kq * 10 + 2 * i];
                pk_fma_lo(acc0, X2[2*i],   xv0); pk_fma_lo(acc1, X2[2*i],   xv1);
                pk_fma_hi(acc0, X2[2*i+1], xv0); pk_fma_hi(acc1, X2[2*i+1], xv1);
            }
        }
        float a00 = acc0.x, a01 = acc0.y, a10 = acc1.x, a11 = acc1.y;
        // k-reduce across the 4 kq lanes of each quad
        a00 += __shfl_xor(a00, 1, 64); a00 += __shfl_xor(a00, 2, 64);
        a01 += __shfl_xor(a01, 1, 64); a01 += __shfl_xor(a01, 2, 64);
        a10 += __shfl_xor(a10, 1, 64); a10 += __shfl_xor(a10, 2, 64);
        a11 += __shfl_xor(a11, 1, 64); a11 += __shfl_xor(a11, 2, 64);
        if (kq == 0) {
            g_red[0][lc0] = a00; g_red[0][lc0 + 1] = a01;
            g_red[1][lc0] = a10; g_red[1][lc0 + 1] = a11;
        }
        __syncthreads();   // B2: g_red ready; FMA reads of h_lds/x_lds done

        // ---- (C) writers: nonlin + c/h update + tagged publish + local h_lds ----
        if (tid < 128) {
            float gi = g_red[cb][      cj] + bc0;
            float gf = g_red[cb][ 64 + cj] + bc1;
            float gg = g_red[cb][128 + cj] + bc2;
            float go = g_red[cb][192 + cj] + bc3;
            float iv = fast_sigmoid(gi), fv = fast_sigmoid(gf), ov = fast_sigmoid(go);
            float gv = fast_tanh(gg);
            c_reg = fmaf(fv, c_reg, iv * gv);
            float hv = ov * fast_tanh(c_reg);
            unsigned u = (__float_as_uint(hv) & ~3u) | (unsigned)(t & 3);
            float* dst = hg + (t & 1) * (BG * H_DIM) + cb * H_DIM + s * 64 + cj;
            asm volatile("global_store_dword %0, %1, off sc0 sc1"
                         :: "v"(dst), "v"(u) : "memory");
            h_lds[cb][s][cj] = __uint_as_float(u);   // own slice: no IC round trip
            outs[((size_t)(batch0 + cb) * T_LEN + t) * H_DIM + s * 64 + cj] =
                __float2bfloat16(hv);
            if (t == T_LEN - 1) {
                out_c[(batch0 + cb) * H_DIM + s * 64 + cj] = c_reg;
                out_h[(batch0 + cb) * H_DIM + s * 64 + cj] = hv;
            }
        }
        // ---- (C) stagers: x(t+1) -> x_lds (FMA readers are already past B2) ----
        if (t + 1 < T_LEN) {
            if (tid >= 384 && tid < 448) {
                int qq = tid - 384, b = qq >> 5, k = qq & 31;
                x_lds[b][k] = z_t[((size_t)(batch0 + b) * T_LEN + (t + 1)) * 32 + k];
            } else if (tid >= 448 && tid < 448 + BG * 3) {
                int qq = tid - 448, b = (qq >= 3), k = qq - 3 * b;
                x_lds[b][32 + k] = a_t[((size_t)(batch0 + b) * T_LEN + (t + 1)) * 3 + k];
            }
        }
        // next iteration's B1 orders all LDS writes; pollers gate on foreign stores
    }
}

// ============ MDN: 16-row kernel with v_pk_fma_f32 over row-pairs ==============
// Same staging / reduction order / epilogue as the proven r6 kernel; the ONLY
// change is the inner loop: w2=(wA,wB) packed once, then per row-pair
//   pk_fma_lo(accA[p], h2, w2)  -> accA += h2 * wA   (broadcast w2.lo)
//   pk_fma_hi(accB[p], h2, w2)  -> accB += h2 * wB   (broadcast w2.hi)
// 32 scalar FMA/k -> 16 packed FMA/k (kernel is VALU-issue-bound).
__global__ __launch_bounds__(256, 1) void mdn_kernel(
    const unsigned short* __restrict__ outputs, const float* __restrict__ Wd,
    const float* __restrict__ bd, float* __restrict__ out)
{
    __shared__ __align__(16) float hT[H_DIM * 16];   // hT[k*16 + r]
    __shared__ float lp[16][K_MIX];

    const int tid = threadIdx.x;
    const long row0 = (long)blockIdx.x * 16;

    for (int idx = tid; idx < H_DIM * 16; idx += 256) {
        int r = idx >> 8;
        int k = idx & (H_DIM - 1);
        unsigned int u = outputs[(row0 + r) * H_DIM + k];
        hT[k * 16 + r] = __uint_as_float(u << 16);
    }
    __syncthreads();

    const int  cA = tid;
    const int  cB = tid + 256;
    const bool vB = (cB < MDN_D);
    const float bA = bd[cA];
    const float bB = vB ? bd[cB] : 0.0f;
    float2v accA[8], accB[8];
    #pragma unroll
    for (int p = 0; p < 8; ++p) {
        accA[p].x = bA; accA[p].y = bA;
        accB[p].x = bB; accB[p].y = bB;
    }

    const float* wpA = Wd + cA;
    const float* wpB = Wd + cB;
    for (int k = 0; k < H_DIM; ++k) {
        float2v w2;
        w2.x = wpA[(size_t)k * MDN_D];
        w2.y = vB ? wpB[(size_t)k * MDN_D] : 0.0f;
        const float2v* hp = (const float2v*)(hT + k * 16);   // uniform -> broadcast
        #pragma unroll
        for (int p = 0; p < 8; ++p) {
            float2v h2 = hp[p];
            pk_fma_lo(accA[p], h2, w2);   // += h2 * wA
            pk_fma_hi(accB[p], h2, w2);   // += h2 * wB
        }
    }

    float* out_mu = out + OFF_MU;
    float* out_sg = out + OFF_SIGMA;
    #pragma unroll
    for (int p = 0; p < 8; ++p) {
        #pragma unroll
        for (int e = 0; e < 2; ++e) {
            int  r   = 2 * p + e;
            long row = row0 + r;
            float v  = e ? accA[p].y : accA[p].x;
            if (cA < K_MIX)            lp[r][cA] = v;
            else if (cA < K_MIX + 160) out_mu[row * 160 + (cA - K_MIX)] = v;
            else                       out_sg[row * 160 + (cA - 165)]   = __expf(v) + 1e-6f;
            if (vB) {
                float vb = e ? accB[p].y : accB[p].x;
                out_sg[row * 160 + (cB - 165)] = __expf(vb) + 1e-6f;
            }
        }
    }
    __syncthreads();

    if (tid < 16) {
        int r = tid;
        long row = row0 + r;
        float v0 = lp[r][0], v1 = lp[r][1], v2 = lp[r][2], v3 = lp[r][3], v4 = lp[r][4];
        float m = fmaxf(fmaxf(fmaxf(v0, v1), fmaxf(v2, v3)), v4);
        float sum = __expf(v0-m) + __expf(v1-m) + __expf(v2-m) + __expf(v3-m) + __expf(v4-m);
        float ls = m + __logf(sum);
        out[row*5 + 0] = v0 - ls;
        out[row*5 + 1] = v1 - ls;
        out[row*5 + 2] = v2 - ls;
        out[row*5 + 3] = v3 - ls;
        out[row*5 + 4] = v4 - ls;
    }
}

extern "C" void kernel_launch(void* const* d_in, const int* in_sizes, int n_in,
                              void* d_out, int out_size, void* d_ws, size_t ws_size,
                              hipStream_t stream)
{
    const float* z_t = (const float*)d_in[0];
    const float* a_t = (const float*)d_in[1];
    const float* Wx  = (const float*)d_in[2];
    const float* Wh  = (const float*)d_in[3];
    const float* b   = (const float*)d_in[4];
    const float* Wd  = (const float*)d_in[5];
    const float* bd  = (const float*)d_in[6];
    float* out = (float*)d_out;

    char* ws = (char*)d_ws;
    __hip_bfloat16* outs = (__hip_bfloat16*)(ws + WS_OUT);
    float* h_glb         = (float*)(ws + WS_HG);

    lstm6_kernel<<<NGRP * NSLICE, 512, 0, stream>>>(z_t, a_t, Wx, Wh, b,
                                                    h_glb, outs,
                                                    out + OFF_C, out + OFF_H);
    mdn_kernel<<<(B_SZ * T_LEN) / 16, 256, 0, stream>>>((const unsigned short*)outs,
                                                        Wd, bd, out);
}

// Round 14
// 1208.671 us; speedup vs baseline: 1.6349x; 1.0544x over previous
//
#include <hip/hip_runtime.h>
#include <hip/hip_bf16.h>
#include <math.h>

// MDN-RNN: B=128, T=512, Z=32, A=3, H=256, K=5, IN=35, 4H=1024, MDN=325
#define T_LEN 512
#define B_SZ  128
#define H_DIM 256
#define G_DIM 1024
#define IN_D  35
#define MDN_D 325
#define K_MIX 5

#define NSLICE 4     // gate-dim slices per group (each owns 64 h-cols x 4 gates)
#define BG     2     // batches per group
#define NGRP   64    // 128 / BG   -> 256 blocks total = 1/CU

// d_out layout: log_pi[B,T,5] | mu[B,T,5,32] | sigma[B,T,5,32] | c[B,256] | h[B,256]
static constexpr long OFF_MU    = 327680L;
static constexpr long OFF_SIGMA = 10813440L;
static constexpr long OFF_C     = 21299200L;
static constexpr long OFF_H     = 21331968L;

// ws layout (~34 MB; ws >= 64 MiB proven in round 1)
static constexpr size_t WS_OUT = 0;          // bf16 outs: B*T*H*2 = 33,554,432 B
static constexpr size_t WS_HG  = 33554432;   // 64 grp * 2 par * 2 b * 256 f32 = 512 KB

typedef unsigned uint2v  __attribute__((ext_vector_type(2)));
typedef float    float2v __attribute__((ext_vector_type(2)));
typedef float    float4v __attribute__((ext_vector_type(4)));

__device__ __forceinline__ float fast_sigmoid(float x) { return 1.0f / (1.0f + __expf(-x)); }
__device__ __forceinline__ float fast_tanh(float x) {
    return 1.0f - 2.0f / (__expf(2.0f * x) + 1.0f);
}

// acc.lo += s0.lo*s1.lo ; acc.hi += s0.hi*s1.LO  (broadcast s1.lo)
__device__ __forceinline__ void pk_fma_lo(float2v& acc, float2v s0, float2v s1) {
    asm("v_pk_fma_f32 %0, %1, %2, %0 op_sel:[0,0,0] op_sel_hi:[1,0,1]"
        : "+v"(acc) : "v"(s0), "v"(s1));
}
// acc.lo += s0.lo*s1.HI ; acc.hi += s0.hi*s1.hi  (broadcast s1.hi)
__device__ __forceinline__ void pk_fma_hi(float2v& acc, float2v s0, float2v s1) {
    asm("v_pk_fma_f32 %0, %1, %2, %0 op_sel:[0,1,0] op_sel_hi:[1,1,1]"
        : "+v"(acc) : "v"(s0), "v"(s1));
}

// ===================== LSTM: round-6 kernel, verbatim (proven 1085 us) ==========
__global__ __launch_bounds__(512, 1) void lstm6_kernel(
    const float* __restrict__ z_t, const float* __restrict__ a_t,
    const float* __restrict__ Wx,  const float* __restrict__ Wh,
    const float* __restrict__ bias,
    float* __restrict__ h_glb,
    __hip_bfloat16* __restrict__ outs,
    float* __restrict__ out_c, float* __restrict__ out_h)
{
    const int bid = blockIdx.x;
    const int gr  = bid & 63;
    const int s   = bid >> 6;
    const int tid = threadIdx.x;
    const int cg  = tid >> 2;              // cols {2cg, 2cg+1} of this 256-col slice
    const int kq  = tid & 3;               // k-range [kq*64, kq*64+64)
    const int lc0 = cg * 2;
    const int gate = lc0 >> 6;
    const int j0   = lc0 & 63;
    const int gcol0 = gate * 256 + s * 64 + j0;

    __shared__ __align__(16) float h_lds[BG][4][68];   // kq sections padded (+4)
    __shared__ __align__(16) float x_lds[BG][44];      // 40 used (4x10 k-split), pad 0
    __shared__ __align__(16) float g_red[BG][256];

    for (int i = tid; i < BG * 4 * 68; i += 512) ((float*)h_lds)[i] = 0.0f;  // h(-1)=0
    if (tid < BG * 9) { int b = tid / 9, k = tid - 9 * b; x_lds[b][35 + k] = 0.0f; }

    // ---- persistent weights in VGPRs: load once, then PIN (no remat possible) ----
    float2v W2[64];
    #pragma unroll
    for (int i = 0; i < 64; ++i) {
        const size_t r = (size_t)(kq * 64 + i) * G_DIM;
        W2[i].x = Wh[r + gcol0];
        W2[i].y = Wh[r + gcol0 + 1];
    }
    float2v X2[10];
    #pragma unroll
    for (int i = 0; i < 10; ++i) {
        int xk = kq * 10 + i;
        bool ok = (xk < IN_D);
        X2[i].x = ok ? Wx[(size_t)xk * G_DIM + gcol0]     : 0.0f;
        X2[i].y = ok ? Wx[(size_t)xk * G_DIM + gcol0 + 1] : 0.0f;
    }
    #pragma unroll
    for (int i = 0; i < 64; ++i) asm volatile("" : "+v"(W2[i]));
    #pragma unroll
    for (int i = 0; i < 10; ++i) asm volatile("" : "+v"(X2[i]));

    // writer role (tid<128): batch cb, h-col cj of this slice
    const int cb = tid >> 6;
    const int cj = tid & 63;
    const float bc0 = bias[0 * 256 + s * 64 + cj];
    const float bc1 = bias[1 * 256 + s * 64 + cj];
    const float bc2 = bias[2 * 256 + s * 64 + cj];
    const float bc3 = bias[3 * 256 + s * 64 + cj];
    float c_reg = 0.0f;

    // poller role (tid in [128,320)): q -> foreign dword pair (b, kk)
    const int q  = tid - 128;              // 0..191
    const int pb = (q >= 96) ? 1 : 0;
    const int pp = q - 96 * pb;            // 0..95
    const int pk0 = pp * 2;
    const int pkk = pk0 + ((pk0 >= s * 64) ? 64 : 0);   // skip own slice's 64-chunk

    const int batch0 = gr * BG;
    float* hg = h_glb + (size_t)gr * (2 * BG * H_DIM);   // [2][BG][256]

    // ---- pre-loop: stage x(0) ----
    if (tid >= 384 && tid < 448) {
        int qq = tid - 384, b = qq >> 5, k = qq & 31;
        x_lds[b][k] = z_t[((size_t)(batch0 + b) * T_LEN + 0) * 32 + k];
    } else if (tid >= 448 && tid < 448 + BG * 3) {
        int qq = tid - 448, b = (qq >= 3), k = qq - 3 * b;
        x_lds[b][32 + k] = a_t[((size_t)(batch0 + b) * T_LEN + 0) * 3 + k];
    }
    __syncthreads();

    for (int t = 0; t < T_LEN; ++t) {
        // ---- (A) pollers fetch foreign h(t-1): self-validating dword pairs ----
        if (t > 0 && tid >= 128 && tid < 320) {
            const unsigned want = (unsigned)((t - 1) & 3);
            const float* ap = hg + ((t - 1) & 1) * (BG * H_DIM) + pb * H_DIM + pkk;
            uint2v u;
            do {
                asm volatile("global_load_dwordx2 %0, %1, off sc0 sc1\n\t"
                             "s_waitcnt vmcnt(0)"
                             : "=v"(u) : "v"(ap) : "memory");
            } while ((u.x & 3u) != want || (u.y & 3u) != want);
            float* dst = &h_lds[pb][pkk >> 6][pkk & 63];
            dst[0] = __uint_as_float(u.x);
            dst[1] = __uint_as_float(u.y);
        }
        __syncthreads();   // B1: h_lds + x_lds(t) ready

        // ---- (B) packed FMA: 2 batches x col-pair x 64 k per thread ----
        float2v acc0 = {0.0f, 0.0f}, acc1 = {0.0f, 0.0f};
        {
            const float4v* hp0 = (const float4v*)h_lds[0][kq];
            const float4v* hp1 = (const float4v*)h_lds[1][kq];
            #pragma unroll
            for (int i4 = 0; i4 < 16; ++i4) {
                float4v hv0 = hp0[i4];
                float4v hv1 = hp1[i4];
                float2v h0lo = __builtin_shufflevector(hv0, hv0, 0, 1);
                float2v h0hi = __builtin_shufflevector(hv0, hv0, 2, 3);
                float2v h1lo = __builtin_shufflevector(hv1, hv1, 0, 1);
                float2v h1hi = __builtin_shufflevector(hv1, hv1, 2, 3);
                pk_fma_lo(acc0, W2[4*i4+0], h0lo); pk_fma_lo(acc1, W2[4*i4+0], h1lo);
                pk_fma_hi(acc0, W2[4*i4+1], h0lo); pk_fma_hi(acc1, W2[4*i4+1], h1lo);
                pk_fma_lo(acc0, W2[4*i4+2], h0hi); pk_fma_lo(acc1, W2[4*i4+2], h1hi);
                pk_fma_hi(acc0, W2[4*i4+3], h0hi); pk_fma_hi(acc1, W2[4*i4+3], h1hi);
            }
            #pragma unroll
            for (int i = 0; i < 5; ++i) {
                float2v xv0 = *(const float2v*)&x_lds[0][kq * 10 + 2 * i];
                float2v xv1 = *(const float2v*)&x_lds[1][kq * 10 + 2 * i];
                pk_fma_lo(acc0, X2[2*i],   xv0); pk_fma_lo(acc1, X2[2*i],   xv1);
                pk_fma_hi(acc0, X2[2*i+1], xv0); pk_fma_hi(acc1, X2[2*i+1], xv1);
            }
        }
        float a00 = acc0.x, a01 = acc0.y, a10 = acc1.x, a11 = acc1.y;
        // k-reduce across the 4 kq lanes of each quad
        a00 += __shfl_xor(a00, 1, 64); a00 += __shfl_xor(a00, 2, 64);
        a01 += __shfl_xor(a01, 1, 64); a01 += __shfl_xor(a01, 2, 64);
        a10 += __shfl_xor(a10, 1, 64); a10 += __shfl_xor(a10, 2, 64);
        a11 += __shfl_xor(a11, 1, 64); a11 += __shfl_xor(a11, 2, 64);
        if (kq == 0) {
            g_red[0][lc0] = a00; g_red[0][lc0 + 1] = a01;
            g_red[1][lc0] = a10; g_red[1][lc0 + 1] = a11;
        }
        __syncthreads();   // B2: g_red ready; FMA reads of h_lds/x_lds done

        // ---- (C) writers: nonlin + c/h update + tagged publish + local h_lds ----
        if (tid < 128) {
            float gi = g_red[cb][      cj] + bc0;
            float gf = g_red[cb][ 64 + cj] + bc1;
            float gg = g_red[cb][128 + cj] + bc2;
            float go = g_red[cb][192 + cj] + bc3;
            float iv = fast_sigmoid(gi), fv = fast_sigmoid(gf), ov = fast_sigmoid(go);
            float gv = fast_tanh(gg);
            c_reg = fmaf(fv, c_reg, iv * gv);
            float hv = ov * fast_tanh(c_reg);
            unsigned u = (__float_as_uint(hv) & ~3u) | (unsigned)(t & 3);
            float* dst = hg + (t & 1) * (BG * H_DIM) + cb * H_DIM + s * 64 + cj;
            asm volatile("global_store_dword %0, %1, off sc0 sc1"
                         :: "v"(dst), "v"(u) : "memory");
            h_lds[cb][s][cj] = __uint_as_float(u);   // own slice: no IC round trip
            outs[((size_t)(batch0 + cb) * T_LEN + t) * H_DIM + s * 64 + cj] =
                __float2bfloat16(hv);
            if (t == T_LEN - 1) {
                out_c[(batch0 + cb) * H_DIM + s * 64 + cj] = c_reg;
                out_h[(batch0 + cb) * H_DIM + s * 64 + cj] = hv;
            }
        }
        // ---- (C) stagers: x(t+1) -> x_lds (FMA readers are already past B2) ----
        if (t + 1 < T_LEN) {
            if (tid >= 384 && tid < 448) {
                int qq = tid - 384, b = qq >> 5, k = qq & 31;
                x_lds[b][k] = z_t[((size_t)(batch0 + b) * T_LEN + (t + 1)) * 32 + k];
            } else if (tid >= 448 && tid < 448 + BG * 3) {
                int qq = tid - 448, b = (qq >= 3), k = qq - 3 * b;
                x_lds[b][32 + k] = a_t[((size_t)(batch0 + b) * T_LEN + (t + 1)) * 3 + k];
            }
        }
        // next iteration's B1 orders all LDS writes; pollers gate on foreign stores
    }
}

// ============ MDN: r6 memory pattern + register-level packed FMA ===============
// IDENTICAL staging, 4x ds_read_b128/k (the r13/r9 regressions were b64 reads),
// identical global pattern and epilogue. Only change: pairs are extracted from
// the loaded float4s in registers (shufflevector = register aliasing) and the
// 32 scalar FMA/k become 16 v_pk_fma_f32/k.
__global__ __launch_bounds__(256, 1) void mdn_kernel(
    const unsigned short* __restrict__ outputs, const float* __restrict__ Wd,
    const float* __restrict__ bd, float* __restrict__ out)
{
    __shared__ __align__(16) float hT[H_DIM * 16];   // hT[k*16 + r]
    __shared__ float lp[16][K_MIX];

    const int tid = threadIdx.x;
    const long row0 = (long)blockIdx.x * 16;

    for (int idx = tid; idx < H_DIM * 16; idx += 256) {
        int r = idx >> 8;
        int k = idx & (H_DIM - 1);
        unsigned int u = outputs[(row0 + r) * H_DIM + k];
        hT[k * 16 + r] = __uint_as_float(u << 16);
    }
    __syncthreads();

    const int  cA = tid;
    const int  cB = tid + 256;
    const bool vB = (cB < MDN_D);
    const float bA = bd[cA];
    const float bB = vB ? bd[cB] : 0.0f;
    float2v accA[8], accB[8];
    #pragma unroll
    for (int p = 0; p < 8; ++p) {
        accA[p].x = bA; accA[p].y = bA;
        accB[p].x = bB; accB[p].y = bB;
    }

    for (int k = 0; k < H_DIM; ++k) {
        float2v w2;
        w2.x = Wd[(size_t)k * MDN_D + cA];
        w2.y = vB ? Wd[(size_t)k * MDN_D + cB] : 0.0f;
        const float4v* hp = (const float4v*)(hT + k * 16);   // 4x b128, as in r6
        float4v h0 = hp[0], h1 = hp[1], h2 = hp[2], h3 = hp[3];
        float2v p;
        p = __builtin_shufflevector(h0, h0, 0, 1);
        pk_fma_lo(accA[0], p, w2); pk_fma_hi(accB[0], p, w2);
        p = __builtin_shufflevector(h0, h0, 2, 3);
        pk_fma_lo(accA[1], p, w2); pk_fma_hi(accB[1], p, w2);
        p = __builtin_shufflevector(h1, h1, 0, 1);
        pk_fma_lo(accA[2], p, w2); pk_fma_hi(accB[2], p, w2);
        p = __builtin_shufflevector(h1, h1, 2, 3);
        pk_fma_lo(accA[3], p, w2); pk_fma_hi(accB[3], p, w2);
        p = __builtin_shufflevector(h2, h2, 0, 1);
        pk_fma_lo(accA[4], p, w2); pk_fma_hi(accB[4], p, w2);
        p = __builtin_shufflevector(h2, h2, 2, 3);
        pk_fma_lo(accA[5], p, w2); pk_fma_hi(accB[5], p, w2);
        p = __builtin_shufflevector(h3, h3, 0, 1);
        pk_fma_lo(accA[6], p, w2); pk_fma_hi(accB[6], p, w2);
        p = __builtin_shufflevector(h3, h3, 2, 3);
        pk_fma_lo(accA[7], p, w2); pk_fma_hi(accB[7], p, w2);
    }

    float* out_mu = out + OFF_MU;
    float* out_sg = out + OFF_SIGMA;
    #pragma unroll
    for (int p = 0; p < 8; ++p) {
        #pragma unroll
        for (int e = 0; e < 2; ++e) {
            int  r   = 2 * p + e;
            long row = row0 + r;
            float v  = e ? accA[p].y : accA[p].x;
            if (cA < K_MIX)            lp[r][cA] = v;
            else if (cA < K_MIX + 160) out_mu[row * 160 + (cA - K_MIX)] = v;
            else                       out_sg[row * 160 + (cA - 165)]   = __expf(v) + 1e-6f;
            if (vB) {
                float vb = e ? accB[p].y : accB[p].x;
                out_sg[row * 160 + (cB - 165)] = __expf(vb) + 1e-6f;
            }
        }
    }
    __syncthreads();

    if (tid < 16) {
        int r = tid;
        long row = row0 + r;
        float v0 = lp[r][0], v1 = lp[r][1], v2 = lp[r][2], v3 = lp[r][3], v4 = lp[r][4];
        float m = fmaxf(fmaxf(fmaxf(v0, v1), fmaxf(v2, v3)), v4);
        float sum = __expf(v0-m) + __expf(v1-m) + __expf(v2-m) + __expf(v3-m) + __expf(v4-m);
        float ls = m + __logf(sum);
        out[row*5 + 0] = v0 - ls;
        out[row*5 + 1] = v1 - ls;
        out[row*5 + 2] = v2 - ls;
        out[row*5 + 3] = v3 - ls;
        out[row*5 + 4] = v4 - ls;
    }
}

extern "C" void kernel_launch(void* const* d_in, const int* in_sizes, int n_in,
                              void* d_out, int out_size, void* d_ws, size_t ws_size,
                              hipStream_t stream)
{
    const float* z_t = (const float*)d_in[0];
    const float* a_t = (const float*)d_in[1];
    const float* Wx  = (const float*)d_in[2];
    const float* Wh  = (const float*)d_in[3];
    const float* b   = (const float*)d_in[4];
    const float* Wd  = (const float*)d_in[5];
    const float* bd  = (const float*)d_in[6];
    float* out = (float*)d_out;

    char* ws = (char*)d_ws;
    __hip_bfloat16* outs = (__hip_bfloat16*)(ws + WS_OUT);
    float* h_glb         = (float*)(ws + WS_HG);

    lstm6_kernel<<<NGRP * NSLICE, 512, 0, stream>>>(z_t, a_t, Wx, Wh, b,
                                                    h_glb, outs,
                                                    out + OFF_C, out + OFF_H);
    mdn_kernel<<<(B_SZ * T_LEN) / 16, 256, 0, stream>>>((const unsigned short*)outs,
                                                        Wd, bd, out);
}